// Round 15
// baseline (402.122 us; speedup 1.0000x reference)
//
#include <hip/hip_runtime.h>

#define HID 32
#define DLAT 97
#define NPG 100
#define TOPK 30
#define BKT_NODES 128   // nodes per bucket (bucket = dst >> 7)
#define BKT_SHIFT 7
#define NBUCK 1024      // bucket table size (ceil(100000/128)=782 used)
#define CAPF 2432       // fixed slots per bucket region (mean 2048, ~8.5 sigma)
#define CHUNK 8192      // edges per partition block

// ---------- single-pass partition: LDS hist + fixed-region reservation ----------
__global__ __launch_bounds__(256) void binB1_kernel(
    const int* __restrict__ src, const int* __restrict__ dst,
    const float* __restrict__ ew, int* __restrict__ gcursor,
    int2* __restrict__ bedge, int E) {
    __shared__ int hist[NBUCK];      // 4 KB
    __shared__ int lcur[NBUCK];      // 4 KB
    __shared__ int dcache[CHUNK];    // 32 KB
    for (int i = threadIdx.x; i < NBUCK; i += 256) hist[i] = 0;
    __syncthreads();
    int base = blockIdx.x * CHUNK;
    int M = min(E - base, CHUNK);
    for (int i = threadIdx.x; i < M; i += 256) {
        int d = dst[base + i];
        dcache[i] = d;
        atomicAdd(&hist[d >> BKT_SHIFT], 1);
    }
    __syncthreads();
    for (int b = threadIdx.x; b < NBUCK; b += 256) {
        int v = hist[b];
        lcur[b] = b * CAPF + (v ? atomicAdd(&gcursor[b], v) : 0);
    }
    __syncthreads();
    for (int i = threadIdx.x; i < M; i += 256) {
        int d = dcache[i];
        int slot = atomicAdd(&lcur[d >> BKT_SHIFT], 1);
        bedge[slot] = make_int2(src[base + i] | ((d & (BKT_NODES - 1)) << 20),
                                __float_as_int(ew[base + i]));
    }
}

// ---------- per-bucket: bucket-scan + counting sort + dinv + fused xw1 ----------
__global__ __launch_bounds__(256) void sortlocal2_kernel(
    const int2* __restrict__ bedge, const int* __restrict__ gcursor,
    const int* __restrict__ z, const float* __restrict__ z_emb,
    const float* __restrict__ W1, int2* __restrict__ csr,
    int* __restrict__ row_start, int* __restrict__ row_deg,
    float* __restrict__ dinv, float* __restrict__ xw_a, int N) {
    __shared__ int2 LDSe[CAPF];          // 19 KB
    __shared__ int sh256[256];
    __shared__ int cnt[BKT_NODES];
    __shared__ int sh2[BKT_NODES];
    __shared__ int lc2[BKT_NODES];
    __shared__ int zloc[BKT_NODES];
    __shared__ float dloc[BKT_NODES];
    __shared__ float W1L[HID * HID];     // 4 KB
    __shared__ int bstart_s;

    int b = blockIdx.x, t = threadIdx.x;

    // redundant exclusive scan over gcursor[1024] -> this bucket's compact csr base
    int t4 = t * 4;
    int a0 = gcursor[t4], a1 = gcursor[t4 + 1], a2 = gcursor[t4 + 2], a3 = gcursor[t4 + 3];
    int tsum = a0 + a1 + a2 + a3;
    sh256[t] = tsum;
    for (int i = t; i < HID * HID; i += 256) W1L[i] = W1[i];
    if (t < BKT_NODES) cnt[t] = 0;
    __syncthreads();
    for (int off = 1; off < 256; off <<= 1) {
        int tv = (t >= off) ? sh256[t - off] : 0;
        __syncthreads();
        sh256[t] += tv;
        __syncthreads();
    }
    if (t == (b >> 2)) {
        int e = sh256[t] - tsum;
        int bb = b & 3;
        if (bb > 0) e += a0;
        if (bb > 1) e += a1;
        if (bb > 2) e += a2;
        bstart_s = e;
    }
    __syncthreads();
    const int begOut = bstart_s;
    const int M = gcursor[b];

    // load bucket edges into LDS + per-node count
    for (int i = t; i < M; i += 256) {
        int2 e = bedge[(size_t)b * CAPF + i];
        LDSe[i] = e;
        atomicAdd(&cnt[(e.x >> 20) & (BKT_NODES - 1)], 1);
    }
    __syncthreads();
    int v = 0, excl = 0;
    int n = b * BKT_NODES + t;
    if (t < BKT_NODES) { v = cnt[t]; sh2[t] = v; }
    __syncthreads();
    for (int off = 1; off < BKT_NODES; off <<= 1) {
        int tv = (t >= off && t < BKT_NODES) ? sh2[t - off] : 0;
        __syncthreads();
        if (t < BKT_NODES) sh2[t] += tv;
        __syncthreads();
    }
    if (t < BKT_NODES) {
        excl = sh2[t] - v;
        lc2[t] = excl;
        if (n < N) {
            row_start[n] = begOut + excl;
            row_deg[n] = v;
        }
    }
    __syncthreads();
    for (int i = t; i < M; i += 256) {
        int2 e = LDSe[i];
        int slot = atomicAdd(&lc2[(e.x >> 20) & (BKT_NODES - 1)], 1);
        csr[begOut + slot] = make_int2(e.x & 0xFFFFF, e.y);
    }
    __syncthreads();  // drain this block's csr writes (same-CU readback, R9-verified)
    if (t < BKT_NODES && n < N) {
        float s = 1.f;
        int s0 = begOut + excl;
        for (int i = 0; i < v; ++i) s += __int_as_float(csr[s0 + i].y);
        float di = 1.f / sqrtf(s);
        dinv[n] = di;
        dloc[t] = di;
        zloc[t] = z[n];
    }
    __syncthreads();
    // fused layer-1 xw (prescaled): xw_a[n][f] = dinv[n]*dot(z_emb[z[n]], W1[:,f])
    int lim = min(BKT_NODES, N - b * BKT_NODES);
    if (lim > 0) {
        for (int idx = t; idx < lim * HID; idx += 256) {
            int nl = idx >> 5, f = idx & 31;
            const float* row = z_emb + (size_t)zloc[nl] * HID;
            float s = 0.f;
#pragma unroll
            for (int k = 0; k < HID; ++k) s += row[k] * W1L[k * HID + f];
            xw_a[(size_t)(b * BKT_NODES + nl) * HID + f] = s * dloc[nl];
        }
    }
}

// ---------------- fused aggregation + next-layer xw GEMM ----------------
// One node per 32-lane half-wave; predicated 8-deep unrolled gathers.
// Node range [n0, n1) per dispatch (split for profiling granularity).
// NOTE (R13): 16-deep unroll raises VGPR 32->44, occupancy 67->44%, dur +19% — keep 8.
template <int MODE>
__global__ __launch_bounds__(256) void agg32f_kernel(
    const int* __restrict__ row_start, const int* __restrict__ row_deg,
    const int2* __restrict__ csr, const float* __restrict__ xw,
    const float* __restrict__ b, const float* __restrict__ dinv,
    const float* __restrict__ Wn, float* __restrict__ concat, int col_off,
    float* __restrict__ xw_next, int n0, int n1) {
    int tid = blockIdx.x * blockDim.x + threadIdx.x;
    int n = n0 + (tid >> 5);
    if (n >= n1) return;
    int f = threadIdx.x & 31;
    int beg = row_start[n];
    int end = beg + row_deg[n];
    float s0 = 0.f, s1 = 0.f;
    for (int i = beg; i < end; i += 8) {
        float w[8];
        int idx[8];
#pragma unroll
        for (int j = 0; j < 8; ++j) {
            int ii = min(i + j, end - 1);   // clamp: duplicate last edge, weight 0
            int2 v = csr[ii];
            idx[j] = v.x;
            w[j] = (i + j < end) ? __int_as_float(v.y) : 0.f;
        }
        float x[8];
#pragma unroll
        for (int j = 0; j < 8; ++j) x[j] = xw[(size_t)idx[j] * HID + f];
#pragma unroll
        for (int j = 0; j < 8; ++j) {
            if (j & 1) s1 += w[j] * x[j];
            else       s0 += w[j] * x[j];
        }
    }
    float s = s0 + s1;
    float di = dinv[n];
    float outv = tanhf(di * (s + xw[(size_t)n * HID + f]) + b[f]);
    concat[(size_t)n * DLAT + col_off + f] = outv;

    if (MODE == 0) {
        float p = 0.f;
#pragma unroll
        for (int k = 0; k < HID; ++k) {
            float ok = __shfl(outv, k, 32);
            p += ok * Wn[k * HID + f];
        }
        xw_next[(size_t)n * HID + f] = p * di;
    } else {
        float p = outv * Wn[f];
        p += __shfl_xor(p, 16);
        p += __shfl_xor(p, 8);
        p += __shfl_xor(p, 4);
        p += __shfl_xor(p, 2);
        p += __shfl_xor(p, 1);
        if (f == 0) xw_next[n] = p * di;
    }
}

// ---- fused: layer-4 agg + tanh + stable top-30 + CNN/MLP head (one block/graph) ----
__global__ __launch_bounds__(128) void topk_head_kernel(
    const int* __restrict__ row_start, const int* __restrict__ row_deg,
    const int2* __restrict__ csr, const float* __restrict__ xw4,
    const float* __restrict__ b4, const float* __restrict__ dinv,
    const float* __restrict__ concat,
    const float* __restrict__ Wc1, const float* __restrict__ bc1,
    const float* __restrict__ Wc2, const float* __restrict__ bc2,
    const float* __restrict__ Wl1, const float* __restrict__ bl1,
    const float* __restrict__ Wl2, const float* __restrict__ bl2,
    float* __restrict__ out) {
    int g = blockIdx.x;
    int tid = threadIdx.x;  // 128 threads
    __shared__ float v[NPG];
    __shared__ int tidx[TOPK];
    __shared__ float tval[TOPK];
    __shared__ float top[TOPK * DLAT];
    __shared__ float y1[16 * TOPK];
    __shared__ float y2[16 * 15];
    __shared__ float y3[352];
    __shared__ float r[128];

    // layer-4 agg: predicated 4-deep unroll
    if (tid < NPG) {
        int n = g * NPG + tid;
        int beg = row_start[n], end = beg + row_deg[n];
        float s0 = 0.f, s1 = 0.f;
        for (int i = beg; i < end; i += 4) {
            int2 e0 = csr[min(i, end - 1)];
            int2 e1 = csr[min(i + 1, end - 1)];
            int2 e2 = csr[min(i + 2, end - 1)];
            int2 e3 = csr[min(i + 3, end - 1)];
            float x0 = xw4[e0.x], x1 = xw4[e1.x], x2 = xw4[e2.x], x3 = xw4[e3.x];
            s0 += __int_as_float(e0.y) * x0;
            if (i + 1 < end) s1 += __int_as_float(e1.y) * x1;
            if (i + 2 < end) s0 += __int_as_float(e2.y) * x2;
            if (i + 3 < end) s1 += __int_as_float(e3.y) * x3;
        }
        v[tid] = tanhf(dinv[n] * ((s0 + s1) + xw4[n]) + b4[0]);
    }
    __syncthreads();
    // stable rank select (matches jnp.argsort(-v): lower index wins ties)
    if (tid < NPG) {
        float vi = v[tid];
        int cnt = 0;
#pragma unroll 4
        for (int j = 0; j < NPG; ++j) {
            float vj = v[j];
            cnt += (vj > vi) || (vj == vi && j < tid);
        }
        if (cnt < TOPK) {
            tidx[cnt] = g * NPG + tid;
            tval[cnt] = vi;
        }
    }
    __syncthreads();

    for (int idx = tid; idx < TOPK * DLAT; idx += 128) {
        int k = idx / DLAT, d = idx - k * DLAT;
        top[idx] = (d == 96) ? tval[k] : concat[(size_t)tidx[k] * DLAT + d];
    }
    __syncthreads();

    for (int idx = tid; idx < 16 * TOPK; idx += 128) {
        int c = idx / TOPK, k = idx % TOPK;
        float s = bc1[c];
        const float* w = Wc1 + c * DLAT;
        const float* t = top + k * DLAT;
#pragma unroll 4
        for (int d = 0; d < DLAT; ++d) s += t[d] * w[d];
        y1[c * TOPK + k] = fmaxf(s, 0.f);
    }
    __syncthreads();

    for (int idx = tid; idx < 16 * 15; idx += 128) {
        int c = idx / 15, j = idx % 15;
        y2[idx] = fmaxf(y1[c * TOPK + 2 * j], y1[c * TOPK + 2 * j + 1]);
    }
    __syncthreads();

    for (int idx = tid; idx < 352; idx += 128) {
        int o = idx / 11, t = idx % 11;
        float s = bc2[o];
#pragma unroll
        for (int i = 0; i < 16; ++i) {
#pragma unroll
            for (int k = 0; k < 5; ++k)
                s += Wc2[(o * 16 + i) * 5 + k] * y2[i * 15 + t + k];
        }
        y3[idx] = fmaxf(s, 0.f);
    }
    __syncthreads();

    {
        float s = bl1[tid];
        for (int d = 0; d < 352; ++d) s += y3[d] * Wl1[d * 128 + tid];
        r[tid] = fmaxf(s, 0.f) * Wl2[tid];
    }
    __syncthreads();
    if (tid < 64) r[tid] += r[tid + 64];
    __syncthreads();
    if (tid == 0) {
        float s = 0.f;
        for (int j = 0; j < 64; ++j) s += r[j];
        out[g] = s + bl2[0];
    }
}

// ---------------- launch ----------------

extern "C" void kernel_launch(void* const* d_in, const int* in_sizes, int n_in,
                              void* d_out, int out_size, void* d_ws, size_t ws_size,
                              hipStream_t stream) {
    const int* z = (const int*)d_in[0];
    const int* ei = (const int*)d_in[1];
    const float* ew = (const float*)d_in[3];
    const float* z_emb = (const float*)d_in[4];
    const float* Wg[4] = {(const float*)d_in[5], (const float*)d_in[7],
                          (const float*)d_in[9], (const float*)d_in[11]};
    const float* bg[4] = {(const float*)d_in[6], (const float*)d_in[8],
                          (const float*)d_in[10], (const float*)d_in[12]};
    const float* Wc1 = (const float*)d_in[13];
    const float* bc1 = (const float*)d_in[14];
    const float* Wc2 = (const float*)d_in[15];
    const float* bc2 = (const float*)d_in[16];
    const float* Wl1 = (const float*)d_in[17];
    const float* bl1 = (const float*)d_in[18];
    const float* Wl2 = (const float*)d_in[19];
    const float* bl2 = (const float*)d_in[20];
    float* out = (float*)d_out;

    const int N = in_sizes[0];
    const int E = in_sizes[1] / 2;
    const int G = out_size;  // 1000 graphs
    const int* src = ei;
    const int* dst = ei + E;

    auto cdiv = [](long long a, long long b) { return (int)((a + b - 1) / b); };
    const int NB = cdiv(E, CHUNK);          // 196 partition blocks
    const int NBKT = cdiv(N, BKT_NODES);    // 782 buckets

    // workspace layout (8B-aligned arrays first)
    char* ws = (char*)d_ws;
    int2* bedge = (int2*)ws;                  ws += sizeof(int2) * (size_t)NBUCK * CAPF;
    int2* csr = (int2*)ws;                    ws += sizeof(int2) * (size_t)E;
    int* gcursor = (int*)ws;                  ws += sizeof(int) * NBUCK;
    int* row_start = (int*)ws;                ws += sizeof(int) * N;
    int* row_deg = (int*)ws;                  ws += sizeof(int) * N;
    float* dinv = (float*)ws;                 ws += sizeof(float) * N;
    float* xw_a = (float*)ws;                 ws += sizeof(float) * (size_t)N * HID;
    float* concat = (float*)ws;               ws += sizeof(float) * (size_t)N * DLAT;
    float* xw4 = (float*)ws;                  ws += sizeof(float) * N;
    // xw ping-pong: B-buffer aliases bedge (dead after sortlocal2; 12.8MB <= 19.9MB)
    float* xw_b = (float*)bedge;

    const int B = 256;

    // single-pass fixed-region partition + per-bucket sort (+scan, dinv, xw1 fused)
    hipMemsetAsync(gcursor, 0, sizeof(int) * NBUCK, stream);
    binB1_kernel<<<NB, B, 0, stream>>>(src, dst, ew, gcursor, bedge, E);
    sortlocal2_kernel<<<NBKT, B, 0, stream>>>(bedge, gcursor, z, z_emb, Wg[0], csr,
                                              row_start, row_deg, dinv, xw_a, N);

    // fused agg+next-xw chain, split into half-node-range dispatches (profiling
    // granularity: drops the top-5 cutoff below the build/head kernels)
    const int NH = (N + 1) / 2;
    const int AGGB_H = cdiv((long long)NH * 32, B);
    agg32f_kernel<0><<<AGGB_H, B, 0, stream>>>(row_start, row_deg, csr, xw_a, bg[0], dinv,
                                               Wg[1], concat, 0, xw_b, 0, NH);
    agg32f_kernel<0><<<AGGB_H, B, 0, stream>>>(row_start, row_deg, csr, xw_a, bg[0], dinv,
                                               Wg[1], concat, 0, xw_b, NH, N);
    agg32f_kernel<0><<<AGGB_H, B, 0, stream>>>(row_start, row_deg, csr, xw_b, bg[1], dinv,
                                               Wg[2], concat, 32, xw_a, 0, NH);
    agg32f_kernel<0><<<AGGB_H, B, 0, stream>>>(row_start, row_deg, csr, xw_b, bg[1], dinv,
                                               Wg[2], concat, 32, xw_a, NH, N);
    agg32f_kernel<1><<<AGGB_H, B, 0, stream>>>(row_start, row_deg, csr, xw_a, bg[2], dinv,
                                               Wg[3], concat, 64, xw4, 0, NH);
    agg32f_kernel<1><<<AGGB_H, B, 0, stream>>>(row_start, row_deg, csr, xw_a, bg[2], dinv,
                                               Wg[3], concat, 64, xw4, NH, N);

    // fused layer-4 agg + tanh + top-30 + head
    topk_head_kernel<<<G, 128, 0, stream>>>(row_start, row_deg, csr, xw4, bg[3], dinv,
                                            concat, Wc1, bc1, Wc2, bc2, Wl1, bl1,
                                            Wl2, bl2, out);
}

// Round 16
// 394.468 us; speedup vs baseline: 1.0194x; 1.0194x over previous
//
#include <hip/hip_runtime.h>

#define HID 32
#define DLAT 97
#define NPG 100
#define TOPK 30
#define BKT_NODES 128   // nodes per bucket (bucket = dst >> 7)
#define BKT_SHIFT 7
#define NBUCK 1024      // bucket table size (ceil(100000/128)=782 used)
#define CAPF 2432       // fixed slots per bucket region (mean 2048, ~8.5 sigma)
#define CHUNK 8192      // edges per partition block

// ---------- single-pass partition: LDS hist + fixed-region reservation ----------
__global__ __launch_bounds__(256) void binB1_kernel(
    const int* __restrict__ src, const int* __restrict__ dst,
    const float* __restrict__ ew, int* __restrict__ gcursor,
    int2* __restrict__ bedge, int E) {
    __shared__ int hist[NBUCK];      // 4 KB
    __shared__ int lcur[NBUCK];      // 4 KB
    __shared__ int dcache[CHUNK];    // 32 KB
    for (int i = threadIdx.x; i < NBUCK; i += 256) hist[i] = 0;
    __syncthreads();
    int base = blockIdx.x * CHUNK;
    int M = min(E - base, CHUNK);
    for (int i = threadIdx.x; i < M; i += 256) {
        int d = dst[base + i];
        dcache[i] = d;
        atomicAdd(&hist[d >> BKT_SHIFT], 1);
    }
    __syncthreads();
    for (int b = threadIdx.x; b < NBUCK; b += 256) {
        int v = hist[b];
        lcur[b] = b * CAPF + (v ? atomicAdd(&gcursor[b], v) : 0);
    }
    __syncthreads();
    for (int i = threadIdx.x; i < M; i += 256) {
        int d = dcache[i];
        int slot = atomicAdd(&lcur[d >> BKT_SHIFT], 1);
        bedge[slot] = make_int2(src[base + i] | ((d & (BKT_NODES - 1)) << 20),
                                __float_as_int(ew[base + i]));
    }
}

// ---------- per-bucket: bucket-scan + counting sort + dinv + fused xw1 ----------
__global__ __launch_bounds__(256) void sortlocal2_kernel(
    const int2* __restrict__ bedge, const int* __restrict__ gcursor,
    const int* __restrict__ z, const float* __restrict__ z_emb,
    const float* __restrict__ W1, int2* __restrict__ csr,
    int* __restrict__ row_start, int* __restrict__ row_deg,
    float* __restrict__ dinv, float* __restrict__ xw_a, int N) {
    __shared__ int2 LDSe[CAPF];          // 19 KB
    __shared__ int sh256[256];
    __shared__ int cnt[BKT_NODES];
    __shared__ int sh2[BKT_NODES];
    __shared__ int lc2[BKT_NODES];
    __shared__ int zloc[BKT_NODES];
    __shared__ float dloc[BKT_NODES];
    __shared__ float W1L[HID * HID];     // 4 KB
    __shared__ int bstart_s;

    int b = blockIdx.x, t = threadIdx.x;

    // redundant exclusive scan over gcursor[1024] -> this bucket's compact csr base
    int t4 = t * 4;
    int a0 = gcursor[t4], a1 = gcursor[t4 + 1], a2 = gcursor[t4 + 2], a3 = gcursor[t4 + 3];
    int tsum = a0 + a1 + a2 + a3;
    sh256[t] = tsum;
    for (int i = t; i < HID * HID; i += 256) W1L[i] = W1[i];
    if (t < BKT_NODES) cnt[t] = 0;
    __syncthreads();
    for (int off = 1; off < 256; off <<= 1) {
        int tv = (t >= off) ? sh256[t - off] : 0;
        __syncthreads();
        sh256[t] += tv;
        __syncthreads();
    }
    if (t == (b >> 2)) {
        int e = sh256[t] - tsum;
        int bb = b & 3;
        if (bb > 0) e += a0;
        if (bb > 1) e += a1;
        if (bb > 2) e += a2;
        bstart_s = e;
    }
    __syncthreads();
    const int begOut = bstart_s;
    const int M = gcursor[b];

    // load bucket edges into LDS + per-node count
    for (int i = t; i < M; i += 256) {
        int2 e = bedge[(size_t)b * CAPF + i];
        LDSe[i] = e;
        atomicAdd(&cnt[(e.x >> 20) & (BKT_NODES - 1)], 1);
    }
    __syncthreads();
    int v = 0, excl = 0;
    int n = b * BKT_NODES + t;
    if (t < BKT_NODES) { v = cnt[t]; sh2[t] = v; }
    __syncthreads();
    for (int off = 1; off < BKT_NODES; off <<= 1) {
        int tv = (t >= off && t < BKT_NODES) ? sh2[t - off] : 0;
        __syncthreads();
        if (t < BKT_NODES) sh2[t] += tv;
        __syncthreads();
    }
    if (t < BKT_NODES) {
        excl = sh2[t] - v;
        lc2[t] = excl;
        if (n < N) {
            row_start[n] = begOut + excl;
            row_deg[n] = v;
        }
    }
    __syncthreads();
    for (int i = t; i < M; i += 256) {
        int2 e = LDSe[i];
        int slot = atomicAdd(&lc2[(e.x >> 20) & (BKT_NODES - 1)], 1);
        csr[begOut + slot] = make_int2(e.x & 0xFFFFF, e.y);
    }
    __syncthreads();  // drain this block's csr writes (same-CU readback, R9-verified)
    if (t < BKT_NODES && n < N) {
        float s = 1.f;
        int s0 = begOut + excl;
        for (int i = 0; i < v; ++i) s += __int_as_float(csr[s0 + i].y);
        float di = 1.f / sqrtf(s);
        dinv[n] = di;
        dloc[t] = di;
        zloc[t] = z[n];
    }
    __syncthreads();
    // fused layer-1 xw (prescaled): xw_a[n][f] = dinv[n]*dot(z_emb[z[n]], W1[:,f])
    int lim = min(BKT_NODES, N - b * BKT_NODES);
    if (lim > 0) {
        for (int idx = t; idx < lim * HID; idx += 256) {
            int nl = idx >> 5, f = idx & 31;
            const float* row = z_emb + (size_t)zloc[nl] * HID;
            float s = 0.f;
#pragma unroll
            for (int k = 0; k < HID; ++k) s += row[k] * W1L[k * HID + f];
            xw_a[(size_t)(b * BKT_NODES + nl) * HID + f] = s * dloc[nl];
        }
    }
}

// ---------------- fused aggregation + next-layer xw GEMM ----------------
// One node per 32-lane half-wave; predicated 8-deep unrolled gathers.
// NOTE (R13): 16-deep unroll raises VGPR 32->44, occupancy 67->44%, dur +19% — keep 8.
template <int MODE>
__global__ __launch_bounds__(256) void agg32f_kernel(
    const int* __restrict__ row_start, const int* __restrict__ row_deg,
    const int2* __restrict__ csr, const float* __restrict__ xw,
    const float* __restrict__ b, const float* __restrict__ dinv,
    const float* __restrict__ Wn, float* __restrict__ concat, int col_off,
    float* __restrict__ xw_next, int N) {
    int tid = blockIdx.x * blockDim.x + threadIdx.x;
    int n = tid >> 5;
    if (n >= N) return;
    int f = threadIdx.x & 31;
    int beg = row_start[n];
    int end = beg + row_deg[n];
    float s0 = 0.f, s1 = 0.f;
    for (int i = beg; i < end; i += 8) {
        float w[8];
        int idx[8];
#pragma unroll
        for (int j = 0; j < 8; ++j) {
            int ii = min(i + j, end - 1);   // clamp: duplicate last edge, weight 0
            int2 v = csr[ii];
            idx[j] = v.x;
            w[j] = (i + j < end) ? __int_as_float(v.y) : 0.f;
        }
        float x[8];
#pragma unroll
        for (int j = 0; j < 8; ++j) x[j] = xw[(size_t)idx[j] * HID + f];
#pragma unroll
        for (int j = 0; j < 8; ++j) {
            if (j & 1) s1 += w[j] * x[j];
            else       s0 += w[j] * x[j];
        }
    }
    float s = s0 + s1;
    float di = dinv[n];
    float outv = tanhf(di * (s + xw[(size_t)n * HID + f]) + b[f]);
    concat[(size_t)n * DLAT + col_off + f] = outv;

    if (MODE == 0) {
        float p = 0.f;
#pragma unroll
        for (int k = 0; k < HID; ++k) {
            float ok = __shfl(outv, k, 32);
            p += ok * Wn[k * HID + f];
        }
        xw_next[(size_t)n * HID + f] = p * di;
    } else {
        float p = outv * Wn[f];
        p += __shfl_xor(p, 16);
        p += __shfl_xor(p, 8);
        p += __shfl_xor(p, 4);
        p += __shfl_xor(p, 2);
        p += __shfl_xor(p, 1);
        if (f == 0) xw_next[n] = p * di;
    }
}

// ---- fused: layer-4 agg + tanh + stable top-30 + CNN/MLP head (one block/graph) ----
__global__ __launch_bounds__(128) void topk_head_kernel(
    const int* __restrict__ row_start, const int* __restrict__ row_deg,
    const int2* __restrict__ csr, const float* __restrict__ xw4,
    const float* __restrict__ b4, const float* __restrict__ dinv,
    const float* __restrict__ concat,
    const float* __restrict__ Wc1, const float* __restrict__ bc1,
    const float* __restrict__ Wc2, const float* __restrict__ bc2,
    const float* __restrict__ Wl1, const float* __restrict__ bl1,
    const float* __restrict__ Wl2, const float* __restrict__ bl2,
    float* __restrict__ out) {
    int g = blockIdx.x;
    int tid = threadIdx.x;  // 128 threads
    __shared__ float v[NPG];
    __shared__ int tidx[TOPK];
    __shared__ float tval[TOPK];
    __shared__ float top[TOPK * DLAT];
    __shared__ float y1[16 * TOPK];
    __shared__ float y2[16 * 15];
    __shared__ float y3[352];
    __shared__ float r[128];

    // layer-4 agg: predicated 4-deep unroll
    if (tid < NPG) {
        int n = g * NPG + tid;
        int beg = row_start[n], end = beg + row_deg[n];
        float s0 = 0.f, s1 = 0.f;
        for (int i = beg; i < end; i += 4) {
            int2 e0 = csr[min(i, end - 1)];
            int2 e1 = csr[min(i + 1, end - 1)];
            int2 e2 = csr[min(i + 2, end - 1)];
            int2 e3 = csr[min(i + 3, end - 1)];
            float x0 = xw4[e0.x], x1 = xw4[e1.x], x2 = xw4[e2.x], x3 = xw4[e3.x];
            s0 += __int_as_float(e0.y) * x0;
            if (i + 1 < end) s1 += __int_as_float(e1.y) * x1;
            if (i + 2 < end) s0 += __int_as_float(e2.y) * x2;
            if (i + 3 < end) s1 += __int_as_float(e3.y) * x3;
        }
        v[tid] = tanhf(dinv[n] * ((s0 + s1) + xw4[n]) + b4[0]);
    }
    __syncthreads();
    // stable rank select (matches jnp.argsort(-v): lower index wins ties)
    if (tid < NPG) {
        float vi = v[tid];
        int cnt = 0;
#pragma unroll 4
        for (int j = 0; j < NPG; ++j) {
            float vj = v[j];
            cnt += (vj > vi) || (vj == vi && j < tid);
        }
        if (cnt < TOPK) {
            tidx[cnt] = g * NPG + tid;
            tval[cnt] = vi;
        }
    }
    __syncthreads();

    // gather top rows (4 independent loads per iteration)
    for (int idx = tid; idx < TOPK * DLAT; idx += 128) {
        int k = idx / DLAT, d = idx - k * DLAT;
        top[idx] = (d == 96) ? tval[k] : concat[(size_t)tidx[k] * DLAT + d];
    }
    __syncthreads();

    for (int idx = tid; idx < 16 * TOPK; idx += 128) {
        int c = idx / TOPK, k = idx % TOPK;
        float s = bc1[c];
        const float* w = Wc1 + c * DLAT;
        const float* t = top + k * DLAT;
#pragma unroll 4
        for (int d = 0; d < DLAT; ++d) s += t[d] * w[d];
        y1[c * TOPK + k] = fmaxf(s, 0.f);
    }
    __syncthreads();

    for (int idx = tid; idx < 16 * 15; idx += 128) {
        int c = idx / 15, j = idx % 15;
        y2[idx] = fmaxf(y1[c * TOPK + 2 * j], y1[c * TOPK + 2 * j + 1]);
    }
    __syncthreads();

    for (int idx = tid; idx < 352; idx += 128) {
        int o = idx / 11, t = idx % 11;
        float s = bc2[o];
#pragma unroll
        for (int i = 0; i < 16; ++i) {
#pragma unroll
            for (int k = 0; k < 5; ++k)
                s += Wc2[(o * 16 + i) * 5 + k] * y2[i * 15 + t + k];
        }
        y3[idx] = fmaxf(s, 0.f);
    }
    __syncthreads();

    // fc1 (352->128): 8-deep explicit unroll — keeps 8 Wl1 loads in flight
    // (R15 diagnosis: serialized Wl1 loads were ~120K cycles of per-block latency)
    {
        float s = bl1[tid];
#pragma unroll 1
        for (int d = 0; d < 352; d += 8) {
            float wv[8], yv[8];
#pragma unroll
            for (int j = 0; j < 8; ++j) wv[j] = Wl1[(d + j) * 128 + tid];
#pragma unroll
            for (int j = 0; j < 8; ++j) yv[j] = y3[d + j];
#pragma unroll
            for (int j = 0; j < 8; ++j) s += yv[j] * wv[j];
        }
        r[tid] = fmaxf(s, 0.f) * Wl2[tid];
    }
    __syncthreads();
    if (tid < 64) r[tid] += r[tid + 64];
    __syncthreads();
    if (tid == 0) {
        float s = 0.f;
        for (int j = 0; j < 64; ++j) s += r[j];
        out[g] = s + bl2[0];
    }
}

// ---------------- launch ----------------

extern "C" void kernel_launch(void* const* d_in, const int* in_sizes, int n_in,
                              void* d_out, int out_size, void* d_ws, size_t ws_size,
                              hipStream_t stream) {
    const int* z = (const int*)d_in[0];
    const int* ei = (const int*)d_in[1];
    const float* ew = (const float*)d_in[3];
    const float* z_emb = (const float*)d_in[4];
    const float* Wg[4] = {(const float*)d_in[5], (const float*)d_in[7],
                          (const float*)d_in[9], (const float*)d_in[11]};
    const float* bg[4] = {(const float*)d_in[6], (const float*)d_in[8],
                          (const float*)d_in[10], (const float*)d_in[12]};
    const float* Wc1 = (const float*)d_in[13];
    const float* bc1 = (const float*)d_in[14];
    const float* Wc2 = (const float*)d_in[15];
    const float* bc2 = (const float*)d_in[16];
    const float* Wl1 = (const float*)d_in[17];
    const float* bl1 = (const float*)d_in[18];
    const float* Wl2 = (const float*)d_in[19];
    const float* bl2 = (const float*)d_in[20];
    float* out = (float*)d_out;

    const int N = in_sizes[0];
    const int E = in_sizes[1] / 2;
    const int G = out_size;  // 1000 graphs
    const int* src = ei;
    const int* dst = ei + E;

    auto cdiv = [](long long a, long long b) { return (int)((a + b - 1) / b); };
    const int NB = cdiv(E, CHUNK);          // 196 partition blocks
    const int NBKT = cdiv(N, BKT_NODES);    // 782 buckets

    // workspace layout (8B-aligned arrays first)
    char* ws = (char*)d_ws;
    int2* bedge = (int2*)ws;                  ws += sizeof(int2) * (size_t)NBUCK * CAPF;
    int2* csr = (int2*)ws;                    ws += sizeof(int2) * (size_t)E;
    int* gcursor = (int*)ws;                  ws += sizeof(int) * NBUCK;
    int* row_start = (int*)ws;                ws += sizeof(int) * N;
    int* row_deg = (int*)ws;                  ws += sizeof(int) * N;
    float* dinv = (float*)ws;                 ws += sizeof(float) * N;
    float* xw_a = (float*)ws;                 ws += sizeof(float) * (size_t)N * HID;
    float* concat = (float*)ws;               ws += sizeof(float) * (size_t)N * DLAT;
    float* xw4 = (float*)ws;                  ws += sizeof(float) * N;
    // xw ping-pong: B-buffer aliases bedge (dead after sortlocal2; 12.8MB <= 19.9MB)
    float* xw_b = (float*)bedge;

    const int B = 256;

    // single-pass fixed-region partition + per-bucket sort (+scan, dinv, xw1 fused)
    hipMemsetAsync(gcursor, 0, sizeof(int) * NBUCK, stream);
    binB1_kernel<<<NB, B, 0, stream>>>(src, dst, ew, gcursor, bedge, E);
    sortlocal2_kernel<<<NBKT, B, 0, stream>>>(bedge, gcursor, z, z_emb, Wg[0], csr,
                                              row_start, row_deg, dinv, xw_a, N);

    // fused agg+next-xw chain (1 node per 32-lane half)
    const int AGGB = cdiv((long long)N * 32, B);
    agg32f_kernel<0><<<AGGB, B, 0, stream>>>(row_start, row_deg, csr, xw_a, bg[0], dinv,
                                             Wg[1], concat, 0, xw_b, N);
    agg32f_kernel<0><<<AGGB, B, 0, stream>>>(row_start, row_deg, csr, xw_b, bg[1], dinv,
                                             Wg[2], concat, 32, xw_a, N);
    agg32f_kernel<1><<<AGGB, B, 0, stream>>>(row_start, row_deg, csr, xw_a, bg[2], dinv,
                                             Wg[3], concat, 64, xw4, N);

    // fused layer-4 agg + tanh + top-30 + head
    topk_head_kernel<<<G, 128, 0, stream>>>(row_start, row_deg, csr, xw4, bg[3], dinv,
                                            concat, Wc1, bc1, Wc2, bc2, Wl1, bl1,
                                            Wl2, bl2, out);
}

// Round 17
// 382.656 us; speedup vs baseline: 1.0509x; 1.0309x over previous
//
#include <hip/hip_runtime.h>

#define HID 32
#define DLAT 97
#define NPG 100
#define TOPK 30
#define BKT_NODES 128   // nodes per bucket (bucket = dst >> 7)
#define BKT_SHIFT 7
#define NBUCK 1024      // bucket table size (ceil(100000/128)=782 used)
#define CAPF 2432       // fixed slots per bucket region (mean 2048, ~8.5 sigma)
#define CHUNK 8192      // edges per partition block

// ---------- single-pass partition: LDS hist + fixed-region reservation ----------
__global__ __launch_bounds__(256) void binB1_kernel(
    const int* __restrict__ src, const int* __restrict__ dst,
    const float* __restrict__ ew, int* __restrict__ gcursor,
    int2* __restrict__ bedge, int E) {
    __shared__ int hist[NBUCK];      // 4 KB
    __shared__ int lcur[NBUCK];      // 4 KB
    __shared__ int dcache[CHUNK];    // 32 KB
    for (int i = threadIdx.x; i < NBUCK; i += 256) hist[i] = 0;
    __syncthreads();
    int base = blockIdx.x * CHUNK;
    int M = min(E - base, CHUNK);
    for (int i = threadIdx.x; i < M; i += 256) {
        int d = dst[base + i];
        dcache[i] = d;
        atomicAdd(&hist[d >> BKT_SHIFT], 1);
    }
    __syncthreads();
    for (int b = threadIdx.x; b < NBUCK; b += 256) {
        int v = hist[b];
        lcur[b] = b * CAPF + (v ? atomicAdd(&gcursor[b], v) : 0);
    }
    __syncthreads();
    for (int i = threadIdx.x; i < M; i += 256) {
        int d = dcache[i];
        int slot = atomicAdd(&lcur[d >> BKT_SHIFT], 1);
        bedge[slot] = make_int2(src[base + i] | ((d & (BKT_NODES - 1)) << 20),
                                __float_as_int(ew[base + i]));
    }
}

// ---------- per-bucket: bucket-scan + counting sort + dinv + fused xw1 ----------
__global__ __launch_bounds__(256) void sortlocal2_kernel(
    const int2* __restrict__ bedge, const int* __restrict__ gcursor,
    const int* __restrict__ z, const float* __restrict__ z_emb,
    const float* __restrict__ W1, int2* __restrict__ csr,
    int* __restrict__ row_start, int* __restrict__ row_deg,
    float* __restrict__ dinv, float* __restrict__ xw_a, int N) {
    __shared__ int2 LDSe[CAPF];          // 19 KB
    __shared__ int sh256[256];
    __shared__ int cnt[BKT_NODES];
    __shared__ int sh2[BKT_NODES];
    __shared__ int lc2[BKT_NODES];
    __shared__ int zloc[BKT_NODES];
    __shared__ float dloc[BKT_NODES];
    __shared__ float W1L[HID * HID];     // 4 KB
    __shared__ int bstart_s;

    int b = blockIdx.x, t = threadIdx.x;

    // redundant exclusive scan over gcursor[1024] -> this bucket's compact csr base
    int t4 = t * 4;
    int a0 = gcursor[t4], a1 = gcursor[t4 + 1], a2 = gcursor[t4 + 2], a3 = gcursor[t4 + 3];
    int tsum = a0 + a1 + a2 + a3;
    sh256[t] = tsum;
    for (int i = t; i < HID * HID; i += 256) W1L[i] = W1[i];
    if (t < BKT_NODES) cnt[t] = 0;
    __syncthreads();
    for (int off = 1; off < 256; off <<= 1) {
        int tv = (t >= off) ? sh256[t - off] : 0;
        __syncthreads();
        sh256[t] += tv;
        __syncthreads();
    }
    if (t == (b >> 2)) {
        int e = sh256[t] - tsum;
        int bb = b & 3;
        if (bb > 0) e += a0;
        if (bb > 1) e += a1;
        if (bb > 2) e += a2;
        bstart_s = e;
    }
    __syncthreads();
    const int begOut = bstart_s;
    const int M = gcursor[b];

    // load bucket edges into LDS + per-node count
    for (int i = t; i < M; i += 256) {
        int2 e = bedge[(size_t)b * CAPF + i];
        LDSe[i] = e;
        atomicAdd(&cnt[(e.x >> 20) & (BKT_NODES - 1)], 1);
    }
    __syncthreads();
    int v = 0, excl = 0;
    int n = b * BKT_NODES + t;
    if (t < BKT_NODES) { v = cnt[t]; sh2[t] = v; }
    __syncthreads();
    for (int off = 1; off < BKT_NODES; off <<= 1) {
        int tv = (t >= off && t < BKT_NODES) ? sh2[t - off] : 0;
        __syncthreads();
        if (t < BKT_NODES) sh2[t] += tv;
        __syncthreads();
    }
    if (t < BKT_NODES) {
        excl = sh2[t] - v;
        lc2[t] = excl;
        if (n < N) {
            row_start[n] = begOut + excl;
            row_deg[n] = v;
        }
    }
    __syncthreads();
    for (int i = t; i < M; i += 256) {
        int2 e = LDSe[i];
        int slot = atomicAdd(&lc2[(e.x >> 20) & (BKT_NODES - 1)], 1);
        csr[begOut + slot] = make_int2(e.x & 0xFFFFF, e.y);
    }
    __syncthreads();  // drain this block's csr writes (same-CU readback, R9-verified)
    if (t < BKT_NODES && n < N) {
        float s = 1.f;
        int s0 = begOut + excl;
        for (int i = 0; i < v; ++i) s += __int_as_float(csr[s0 + i].y);
        float di = 1.f / sqrtf(s);
        dinv[n] = di;
        dloc[t] = di;
        zloc[t] = z[n];
    }
    __syncthreads();
    // fused layer-1 xw (prescaled): xw_a[n][f] = dinv[n]*dot(z_emb[z[n]], W1[:,f])
    int lim = min(BKT_NODES, N - b * BKT_NODES);
    if (lim > 0) {
        for (int idx = t; idx < lim * HID; idx += 256) {
            int nl = idx >> 5, f = idx & 31;
            const float* row = z_emb + (size_t)zloc[nl] * HID;
            float s = 0.f;
#pragma unroll
            for (int k = 0; k < HID; ++k) s += row[k] * W1L[k * HID + f];
            xw_a[(size_t)(b * BKT_NODES + nl) * HID + f] = s * dloc[nl];
        }
    }
}

// ---------------- fused aggregation + next-layer xw GEMM ----------------
// One node per 32-lane half-wave; predicated 8-deep unrolled gathers.
// NOTE (R13): 16-deep unroll raises VGPR 32->44, occupancy 67->44%, dur +19% — keep 8.
template <int MODE>
__global__ __launch_bounds__(256) void agg32f_kernel(
    const int* __restrict__ row_start, const int* __restrict__ row_deg,
    const int2* __restrict__ csr, const float* __restrict__ xw,
    const float* __restrict__ b, const float* __restrict__ dinv,
    const float* __restrict__ Wn, float* __restrict__ concat, int col_off,
    float* __restrict__ xw_next, int N) {
    int tid = blockIdx.x * blockDim.x + threadIdx.x;
    int n = tid >> 5;
    if (n >= N) return;
    int f = threadIdx.x & 31;
    int beg = row_start[n];
    int end = beg + row_deg[n];
    float s0 = 0.f, s1 = 0.f;
    for (int i = beg; i < end; i += 8) {
        float w[8];
        int idx[8];
#pragma unroll
        for (int j = 0; j < 8; ++j) {
            int ii = min(i + j, end - 1);   // clamp: duplicate last edge, weight 0
            int2 v = csr[ii];
            idx[j] = v.x;
            w[j] = (i + j < end) ? __int_as_float(v.y) : 0.f;
        }
        float x[8];
#pragma unroll
        for (int j = 0; j < 8; ++j) x[j] = xw[(size_t)idx[j] * HID + f];
#pragma unroll
        for (int j = 0; j < 8; ++j) {
            if (j & 1) s1 += w[j] * x[j];
            else       s0 += w[j] * x[j];
        }
    }
    float s = s0 + s1;
    float di = dinv[n];
    float outv = tanhf(di * (s + xw[(size_t)n * HID + f]) + b[f]);
    concat[(size_t)n * DLAT + col_off + f] = outv;

    if (MODE == 0) {
        float p = 0.f;
#pragma unroll
        for (int k = 0; k < HID; ++k) {
            float ok = __shfl(outv, k, 32);
            p += ok * Wn[k * HID + f];
        }
        xw_next[(size_t)n * HID + f] = p * di;
    } else {
        float p = outv * Wn[f];
        p += __shfl_xor(p, 16);
        p += __shfl_xor(p, 8);
        p += __shfl_xor(p, 4);
        p += __shfl_xor(p, 2);
        p += __shfl_xor(p, 1);
        if (f == 0) xw_next[n] = p * di;
    }
}

// ---- fused: layer-4 agg + tanh + stable top-30 + CNN/MLP head ----
// 256 threads/block (R17): Wc1/Wc2 staged in LDS (conv loops go LDS-only),
// fc1 split 2-way across thread pairs. LDS ~34 KB -> 4 blocks/CU.
__global__ __launch_bounds__(256) void topk_head_kernel(
    const int* __restrict__ row_start, const int* __restrict__ row_deg,
    const int2* __restrict__ csr, const float* __restrict__ xw4,
    const float* __restrict__ b4, const float* __restrict__ dinv,
    const float* __restrict__ concat,
    const float* __restrict__ Wc1, const float* __restrict__ bc1,
    const float* __restrict__ Wc2, const float* __restrict__ bc2,
    const float* __restrict__ Wl1, const float* __restrict__ bl1,
    const float* __restrict__ Wl2, const float* __restrict__ bl2,
    float* __restrict__ out) {
    int g = blockIdx.x;
    int tid = threadIdx.x;  // 256 threads
    __shared__ float v[NPG];
    __shared__ int tidx[TOPK];
    __shared__ float tval[TOPK];
    __shared__ float top[TOPK * DLAT];   // 11.6 KB
    __shared__ float Wc1L[16 * DLAT];    // 6.2 KB
    __shared__ float Wc2L[32 * 16 * 5];  // 10.2 KB
    __shared__ float y1[16 * TOPK];
    __shared__ float y2[16 * 15];
    __shared__ float y3[352];
    __shared__ float r[256];

    // stage conv weights (read once per block; graph-independent broadcast)
    for (int i = tid; i < 16 * DLAT; i += 256) Wc1L[i] = Wc1[i];
    for (int i = tid; i < 32 * 16 * 5; i += 256) Wc2L[i] = Wc2[i];

    // layer-4 agg: predicated 4-deep unroll (tid < 100)
    if (tid < NPG) {
        int n = g * NPG + tid;
        int beg = row_start[n], end = beg + row_deg[n];
        float s0 = 0.f, s1 = 0.f;
        for (int i = beg; i < end; i += 4) {
            int2 e0 = csr[min(i, end - 1)];
            int2 e1 = csr[min(i + 1, end - 1)];
            int2 e2 = csr[min(i + 2, end - 1)];
            int2 e3 = csr[min(i + 3, end - 1)];
            float x0 = xw4[e0.x], x1 = xw4[e1.x], x2 = xw4[e2.x], x3 = xw4[e3.x];
            s0 += __int_as_float(e0.y) * x0;
            if (i + 1 < end) s1 += __int_as_float(e1.y) * x1;
            if (i + 2 < end) s0 += __int_as_float(e2.y) * x2;
            if (i + 3 < end) s1 += __int_as_float(e3.y) * x3;
        }
        v[tid] = tanhf(dinv[n] * ((s0 + s1) + xw4[n]) + b4[0]);
    }
    __syncthreads();
    // stable rank select (matches jnp.argsort(-v): lower index wins ties)
    if (tid < NPG) {
        float vi = v[tid];
        int cnt = 0;
#pragma unroll 4
        for (int j = 0; j < NPG; ++j) {
            float vj = v[j];
            cnt += (vj > vi) || (vj == vi && j < tid);
        }
        if (cnt < TOPK) {
            tidx[cnt] = g * NPG + tid;
            tval[cnt] = vi;
        }
    }
    __syncthreads();

    for (int idx = tid; idx < TOPK * DLAT; idx += 256) {
        int k = idx / DLAT, d = idx - k * DLAT;
        top[idx] = (d == 96) ? tval[k] : concat[(size_t)tidx[k] * DLAT + d];
    }
    __syncthreads();

    // conv1 (LDS-only): y1[c][k] = relu(dot(top[k], Wc1L[c]) + bc1[c])
    for (int idx = tid; idx < 16 * TOPK; idx += 256) {
        int c = idx / TOPK, k = idx % TOPK;
        float s = bc1[c];
        const float* w = Wc1L + c * DLAT;
        const float* t = top + k * DLAT;
#pragma unroll 4
        for (int d = 0; d < DLAT; ++d) s += t[d] * w[d];
        y1[c * TOPK + k] = fmaxf(s, 0.f);
    }
    __syncthreads();

    for (int idx = tid; idx < 16 * 15; idx += 256) {
        int c = idx / 15, j = idx % 15;
        y2[idx] = fmaxf(y1[c * TOPK + 2 * j], y1[c * TOPK + 2 * j + 1]);
    }
    __syncthreads();

    // conv2 (LDS-only)
    for (int idx = tid; idx < 352; idx += 256) {
        int o = idx / 11, t = idx % 11;
        float s = bc2[o];
#pragma unroll
        for (int i = 0; i < 16; ++i) {
#pragma unroll
            for (int k = 0; k < 5; ++k)
                s += Wc2L[(o * 16 + i) * 5 + k] * y2[i * 15 + t + k];
        }
        y3[idx] = fmaxf(s, 0.f);
    }
    __syncthreads();

    // fc1 (352->128) split 2-way: pair (o, o+128) sums halves of d-range
    {
        int half = tid >> 7;          // 0 or 1
        int o = tid & 127;
        int d0 = half * 176;
        float s = (half == 0) ? bl1[o] : 0.f;
#pragma unroll 1
        for (int d = d0; d < d0 + 176; d += 8) {
            float wv[8], yv[8];
#pragma unroll
            for (int j = 0; j < 8; ++j) wv[j] = Wl1[(d + j) * 128 + o];
#pragma unroll
            for (int j = 0; j < 8; ++j) yv[j] = y3[d + j];
#pragma unroll
            for (int j = 0; j < 8; ++j) s += yv[j] * wv[j];
        }
        r[tid] = s;
    }
    __syncthreads();
    if (tid < 128) r[tid] = fmaxf(r[tid] + r[tid + 128], 0.f) * Wl2[tid];
    __syncthreads();
    if (tid < 64) r[tid] += r[tid + 64];
    __syncthreads();
    if (tid == 0) {
        float s = 0.f;
        for (int j = 0; j < 64; ++j) s += r[j];
        out[g] = s + bl2[0];
    }
}

// ---------------- launch ----------------

extern "C" void kernel_launch(void* const* d_in, const int* in_sizes, int n_in,
                              void* d_out, int out_size, void* d_ws, size_t ws_size,
                              hipStream_t stream) {
    const int* z = (const int*)d_in[0];
    const int* ei = (const int*)d_in[1];
    const float* ew = (const float*)d_in[3];
    const float* z_emb = (const float*)d_in[4];
    const float* Wg[4] = {(const float*)d_in[5], (const float*)d_in[7],
                          (const float*)d_in[9], (const float*)d_in[11]};
    const float* bg[4] = {(const float*)d_in[6], (const float*)d_in[8],
                          (const float*)d_in[10], (const float*)d_in[12]};
    const float* Wc1 = (const float*)d_in[13];
    const float* bc1 = (const float*)d_in[14];
    const float* Wc2 = (const float*)d_in[15];
    const float* bc2 = (const float*)d_in[16];
    const float* Wl1 = (const float*)d_in[17];
    const float* bl1 = (const float*)d_in[18];
    const float* Wl2 = (const float*)d_in[19];
    const float* bl2 = (const float*)d_in[20];
    float* out = (float*)d_out;

    const int N = in_sizes[0];
    const int E = in_sizes[1] / 2;
    const int G = out_size;  // 1000 graphs
    const int* src = ei;
    const int* dst = ei + E;

    auto cdiv = [](long long a, long long b) { return (int)((a + b - 1) / b); };
    const int NB = cdiv(E, CHUNK);          // 196 partition blocks
    const int NBKT = cdiv(N, BKT_NODES);    // 782 buckets

    // workspace layout (8B-aligned arrays first)
    char* ws = (char*)d_ws;
    int2* bedge = (int2*)ws;                  ws += sizeof(int2) * (size_t)NBUCK * CAPF;
    int2* csr = (int2*)ws;                    ws += sizeof(int2) * (size_t)E;
    int* gcursor = (int*)ws;                  ws += sizeof(int) * NBUCK;
    int* row_start = (int*)ws;                ws += sizeof(int) * N;
    int* row_deg = (int*)ws;                  ws += sizeof(int) * N;
    float* dinv = (float*)ws;                 ws += sizeof(float) * N;
    float* xw_a = (float*)ws;                 ws += sizeof(float) * (size_t)N * HID;
    float* concat = (float*)ws;               ws += sizeof(float) * (size_t)N * DLAT;
    float* xw4 = (float*)ws;                  ws += sizeof(float) * N;
    // xw ping-pong: B-buffer aliases bedge (dead after sortlocal2; 12.8MB <= 19.9MB)
    float* xw_b = (float*)bedge;

    const int B = 256;

    // single-pass fixed-region partition + per-bucket sort (+scan, dinv, xw1 fused)
    hipMemsetAsync(gcursor, 0, sizeof(int) * NBUCK, stream);
    binB1_kernel<<<NB, B, 0, stream>>>(src, dst, ew, gcursor, bedge, E);
    sortlocal2_kernel<<<NBKT, B, 0, stream>>>(bedge, gcursor, z, z_emb, Wg[0], csr,
                                              row_start, row_deg, dinv, xw_a, N);

    // fused agg+next-xw chain (1 node per 32-lane half)
    const int AGGB = cdiv((long long)N * 32, B);
    agg32f_kernel<0><<<AGGB, B, 0, stream>>>(row_start, row_deg, csr, xw_a, bg[0], dinv,
                                             Wg[1], concat, 0, xw_b, N);
    agg32f_kernel<0><<<AGGB, B, 0, stream>>>(row_start, row_deg, csr, xw_b, bg[1], dinv,
                                             Wg[2], concat, 32, xw_a, N);
    agg32f_kernel<1><<<AGGB, B, 0, stream>>>(row_start, row_deg, csr, xw_a, bg[2], dinv,
                                             Wg[3], concat, 64, xw4, N);

    // fused layer-4 agg + tanh + top-30 + head (256 threads/block)
    topk_head_kernel<<<G, 256, 0, stream>>>(row_start, row_deg, csr, xw4, bg[3], dinv,
                                            concat, Wc1, bc1, Wc2, bc2, Wl1, bl1,
                                            Wl2, bl2, out);
}